// Round 3
// baseline (121.243 us; speedup 1.0000x reference)
//
#include <hip/hip_runtime.h>
#include <math.h>

#define MB_    32
#define ATOM_  64
#define HID_   64
#define NRBF_  300
#define GAMMA_ 10.0f
#define RES_   0.1f

// filter table: f2(d) sampled at TPTS points, step TSTEP, domain [0, 10]
// stored interleaved: Tp[s*128 + 2c] = f2(s)[c], Tp[s*128 + 2c + 1] = f2(s+1)[c]
#define TPTS      2001
#define TSTEP     0.005f
#define INV_TSTEP 200.0f

// workspace layout (float offsets)
#define T_OFF   0
#define T_SZ    (TPTS * 128)         // 256128 (float2-interleaved)
#define V1_OFF  (T_OFF + T_SZ)
#define V1_SZ   (MB_ * 64 * 64)      // 131072
#define W2T_OFF (V1_OFF + V1_SZ)
#define W3T_OFF (W2T_OFF + 4096)
// total 395392 floats = 1.58 MB of d_ws

__device__ __forceinline__ float sp_f(float x) {
    return fmaxf(x, 0.f) + log1pf(__expf(-fabsf(x)));
}

// ---------------------------------------------------------------------------
// prep: blocks [0,32)   -> v1[m] = x[m] @ W1^T + b1            (f32, exact)
//       blocks [32,533) -> filter table rows (4 d-samples each, interleaved)
//       block  533      -> W2^T, W3^T for coalesced tail reads
// ---------------------------------------------------------------------------
__global__ __launch_bounds__(256)
void schnet_prep(const float* __restrict__ x,   const float* __restrict__ W1,
                 const float* __restrict__ b1,  const float* __restrict__ W2,
                 const float* __restrict__ W3,  const float* __restrict__ Wd1,
                 const float* __restrict__ bd1, const float* __restrict__ Wd2,
                 const float* __restrict__ bd2, float* __restrict__ ws)
{
    __shared__ float smem[8256];     // 33 KB, unioned between branches
    const int tid = threadIdx.x;
    const int b   = blockIdx.x;

    if (b < MB_) {
        // ---- v1 = x[m] @ W1^T + b1 ----
        float* sx = smem;            // [64][64]
        float* sw = smem + 4096;     // W1^T, [c][o] stride 65 (conflict-free)
        const float* xm = x + b * 4096;
        for (int e = tid; e < 1024; e += 256)
            ((float4*)sx)[e] = ((const float4*)xm)[e];
        for (int e = tid; e < 4096; e += 256) {
            int o = e >> 6, c = e & 63;
            sw[c * 65 + o] = W1[e];
        }
        __syncthreads();
        const int o = tid & 63, p = tid >> 6;
        const float bo = b1[o];
        for (int ii = 0; ii < 16; ++ii) {
            const int i = p * 16 + ii;
            float a0 = bo, a1 = 0.f;
            #pragma unroll
            for (int c = 0; c < 64; c += 2) {
                a0 = fmaf(sx[i * 64 + c],     sw[c * 65 + o],       a0);
                a1 = fmaf(sx[i * 64 + c + 1], sw[(c + 1) * 65 + o], a1);
            }
            ws[V1_OFF + (b * 64 + i) * 64 + o] = a0 + a1;
        }
    } else if (b < MB_ + 501) {
        // ---- table: 4 d-samples per block (one per wave) ----
        float* rbf = smem;           // [4][320] (300 real + zero pad)
        float* u   = smem + 1280;    // [4][64]
        float* wt  = smem + 1536;    // [64][65] chunk buffer (Wd1^T then Wd2^T)
        const int sub = tid >> 6, lane = tid & 63;
        const int s = (b - MB_) * 4 + sub;
        const bool live = (s < TPTS);
        const float d = live ? s * TSTEP : 0.f;

        if (live) {
            for (int r = lane; r < NRBF_; r += 64) {
                float t = fmaf(-RES_, (float)r, d);
                rbf[sub * 320 + r] = __expf(-GAMMA_ * t * t);
            }
            if (lane < 20) rbf[sub * 320 + 300 + lane] = 0.f;   // pad
        }
        float a0 = live ? bd1[lane] : 0.f, a1 = 0.f;
        for (int r0 = 0; r0 < 320; r0 += 64) {
            __syncthreads();         // WAR on wt
            for (int e = tid; e < 4096; e += 256) {
                int h = e >> 6, rr = e & 63;
                int r = r0 + rr;
                wt[rr * 65 + h] = (r < NRBF_) ? Wd1[h * NRBF_ + r] : 0.f;
            }
            __syncthreads();         // RAW on wt
            if (live) {
                #pragma unroll
                for (int rr = 0; rr < 64; rr += 2) {
                    a0 = fmaf(wt[rr * 65 + lane],       rbf[sub * 320 + r0 + rr],     a0);
                    a1 = fmaf(wt[(rr + 1) * 65 + lane], rbf[sub * 320 + r0 + rr + 1], a1);
                }
            }
        }
        if (live) u[sub * 64 + lane] = sp_f(a0 + a1);
        __syncthreads();
        // stage Wd2^T into wt (reuse)
        for (int e = tid; e < 4096; e += 256) {
            int o = e >> 6, c = e & 63;
            wt[c * 65 + o] = Wd2[e];
        }
        __syncthreads();
        if (live) {
            float c0 = bd2[lane], c1 = 0.f;
            #pragma unroll
            for (int h1 = 0; h1 < 64; h1 += 2) {
                c0 = fmaf(wt[h1 * 65 + lane],       u[sub * 64 + h1],     c0);
                c1 = fmaf(wt[(h1 + 1) * 65 + lane], u[sub * 64 + h1 + 1], c1);
            }
            float val = sp_f(c0 + c1);
            // interleaved write: t0 slot of row s, t1 slot of row s-1
            ws[T_OFF + s * 128 + 2 * lane] = val;
            if (s > 0) ws[T_OFF + (s - 1) * 128 + 2 * lane + 1] = val;
        }
    } else {
        // ---- transpose W2, W3 ----
        for (int e = tid; e < 4096; e += 256) {
            int o = e >> 6, c = e & 63;
            ws[W2T_OFF + c * 64 + o] = W2[e];
            ws[W3T_OFF + c * 64 + o] = W3[e];
        }
    }
}

// ---------------------------------------------------------------------------
// main: one block per (m, j).  agg[c] = sum_i v1[m,i,c] * lerp(T, d_ij)[c]
//       then v2 = sp(agg @ W2^T + b2); out = x + v2 @ W3^T + b3
// ---------------------------------------------------------------------------
__global__ __launch_bounds__(256)
void schnet_main(const float* __restrict__ x, const float* __restrict__ dist,
                 const float* __restrict__ b2, const float* __restrict__ b3,
                 const float* __restrict__ ws, float* __restrict__ out)
{
    __shared__ float sRed[4 * 64];
    __shared__ float sAgg[64];
    const int m   = blockIdx.x >> 6;
    const int j   = blockIdx.x & 63;
    const int tid = threadIdx.x;
    const int c   = tid & 63;        // channel this thread owns (lane)
    const int p   = tid >> 6;        // wave = i-quarter

    // this wave's 16 distances, held in lanes 0..15 (replicated)
    float dv = dist[(m * ATOM_ + p * 16 + (c & 15)) * ATOM_ + j];

    const float* Tb  = ws + T_OFF;
    const float* v1m = ws + V1_OFF + (m * 64 + p * 16) * 64;
    float acc = 0.f;
    #pragma unroll
    for (int ii = 0; ii < 16; ++ii) {
        float d  = __shfl(dv, ii, 64);              // broadcast from lane ii
        float f  = d * INV_TSTEP;
        int   s  = min((int)f, TPTS - 2);
        float fr = f - (float)s;
        float2 tv = *(const float2*)(Tb + s * 128 + 2 * c);   // (t0, t1) one 8B load
        float f2v = fmaf(fr, tv.y - tv.x, tv.x);
        acc = fmaf(f2v, v1m[ii * 64 + c], acc);     // coalesced, L1/L2-hit
    }
    sRed[p * 64 + c] = acc;
    __syncthreads();
    if (tid < 64)
        sAgg[tid] = sRed[tid] + sRed[64 + tid] + sRed[128 + tid] + sRed[192 + tid];
    __syncthreads();

    // v2_pre = agg @ W2^T : thread (o=c, quarter=p) does 16 MACs, coalesced W2T
    {
        const float* W2t = ws + W2T_OFF;
        float s_ = 0.f;
        #pragma unroll
        for (int cc = 0; cc < 16; ++cc)
            s_ = fmaf(sAgg[16 * p + cc], W2t[(16 * p + cc) * 64 + c], s_);
        sRed[p * 64 + c] = s_;
    }
    __syncthreads();
    if (tid < 64)
        sAgg[tid] = sp_f(sRed[tid] + sRed[64 + tid] + sRed[128 + tid] + sRed[192 + tid] + b2[tid]);
    __syncthreads();
    {
        const float* W3t = ws + W3T_OFF;
        float s_ = 0.f;
        #pragma unroll
        for (int cc = 0; cc < 16; ++cc)
            s_ = fmaf(sAgg[16 * p + cc], W3t[(16 * p + cc) * 64 + c], s_);
        sRed[p * 64 + c] = s_;
    }
    __syncthreads();
    if (tid < 64) {
        float v_ = sRed[tid] + sRed[64 + tid] + sRed[128 + tid] + sRed[192 + tid] + b3[tid];
        out[(m * ATOM_ + j) * HID_ + tid] = v_ + x[(m * ATOM_ + j) * HID_ + tid];
    }
}

extern "C" void kernel_launch(void* const* d_in, const int* in_sizes, int n_in,
                              void* d_out, int out_size, void* d_ws, size_t ws_size,
                              hipStream_t stream) {
    const float* x   = (const float*)d_in[0];
    const float* dist= (const float*)d_in[1];
    const float* W1  = (const float*)d_in[2];
    const float* b1  = (const float*)d_in[3];
    const float* W2  = (const float*)d_in[4];
    const float* b2  = (const float*)d_in[5];
    const float* W3  = (const float*)d_in[6];
    const float* b3  = (const float*)d_in[7];
    const float* Wd1 = (const float*)d_in[8];
    const float* bd1 = (const float*)d_in[9];
    const float* Wd2 = (const float*)d_in[10];
    const float* bd2 = (const float*)d_in[11];
    float* out = (float*)d_out;
    float* ws  = (float*)d_ws;
    (void)in_sizes; (void)n_in; (void)out_size; (void)ws_size;
    // needs ~1.58 MB of d_ws (interleaved table + v1 + W2^T/W3^T)

    schnet_prep<<<dim3(MB_ + 501 + 1), dim3(256), 0, stream>>>(
        x, W1, b1, W2, W3, Wd1, bd1, Wd2, bd2, ws);
    schnet_main<<<dim3(MB_ * ATOM_), dim3(256), 0, stream>>>(
        x, dist, b2, b3, ws, out);
}

// Round 4
// 115.259 us; speedup vs baseline: 1.0519x; 1.0519x over previous
//
#include <hip/hip_runtime.h>
#include <math.h>

#define MB_    32
#define ATOM_  64
#define HID_   64
#define NRBF_  300
#define GAMMA_ 10.0f
#define RES_   0.1f

// filter table: f2(d) sampled at TPTS points, step TSTEP, domain [0, 10]
#define TPTS      2001
#define TSTEP     0.005f
#define INV_TSTEP 200.0f

// workspace layout (float offsets)
#define T_OFF   0
#define T_SZ    (TPTS * 64)          // 128064
#define V1_OFF  (T_OFF + T_SZ)       // 128064
#define V1_SZ   (MB_ * 64 * 64)      // 131072
#define W2T_OFF (V1_OFF + V1_SZ)     // 259136
#define W3T_OFF (W2T_OFF + 4096)     // 263232
// total 267328 floats = 1,069,312 bytes of d_ws

__device__ __forceinline__ float sp_f(float x) {
    return fmaxf(x, 0.f) + log1pf(__expf(-fabsf(x)));
}

// ---------------------------------------------------------------------------
// prep: blocks [0,32)   -> v1[m] = x[m] @ W1^T + b1            (f32, exact)
//       blocks [32,533) -> filter table rows (4 d-samples each)
//       block  533      -> W2^T, W3^T for coalesced tail reads
// ---------------------------------------------------------------------------
__global__ __launch_bounds__(256)
void schnet_prep(const float* __restrict__ x,   const float* __restrict__ W1,
                 const float* __restrict__ b1,  const float* __restrict__ W2,
                 const float* __restrict__ W3,  const float* __restrict__ Wd1,
                 const float* __restrict__ bd1, const float* __restrict__ Wd2,
                 const float* __restrict__ bd2, float* __restrict__ ws)
{
    __shared__ float smem[8256];     // 33 KB, unioned between branches
    const int tid = threadIdx.x;
    const int b   = blockIdx.x;

    if (b < MB_) {
        // ---- v1 = x[m] @ W1^T + b1 ----
        float* sx = smem;            // [64][64]
        float* sw = smem + 4096;     // W1^T, [c][o] stride 65 (conflict-free)
        const float* xm = x + b * 4096;
        for (int e = tid; e < 1024; e += 256)
            ((float4*)sx)[e] = ((const float4*)xm)[e];
        for (int e = tid; e < 4096; e += 256) {
            int o = e >> 6, c = e & 63;
            sw[c * 65 + o] = W1[e];
        }
        __syncthreads();
        const int o = tid & 63, p = tid >> 6;
        const float bo = b1[o];
        for (int ii = 0; ii < 16; ++ii) {
            const int i = p * 16 + ii;
            float a0 = bo, a1 = 0.f;
            #pragma unroll
            for (int c = 0; c < 64; c += 2) {
                a0 = fmaf(sx[i * 64 + c],     sw[c * 65 + o],       a0);
                a1 = fmaf(sx[i * 64 + c + 1], sw[(c + 1) * 65 + o], a1);
            }
            ws[V1_OFF + (b * 64 + i) * 64 + o] = a0 + a1;
        }
    } else if (b < MB_ + 501) {
        // ---- table: 4 d-samples per block (one per wave) ----
        float* rbf = smem;           // [4][320] (300 real + zero pad)
        float* u   = smem + 1280;    // [4][64]
        float* wt  = smem + 1536;    // [64][65] chunk buffer (Wd1^T then Wd2^T)
        const int sub = tid >> 6, lane = tid & 63;
        const int s = (b - MB_) * 4 + sub;
        const bool live = (s < TPTS);
        const float d = live ? s * TSTEP : 0.f;

        if (live) {
            for (int r = lane; r < NRBF_; r += 64) {
                float t = fmaf(-RES_, (float)r, d);
                rbf[sub * 320 + r] = __expf(-GAMMA_ * t * t);
            }
            if (lane < 20) rbf[sub * 320 + 300 + lane] = 0.f;   // pad
        }
        float a0 = live ? bd1[lane] : 0.f, a1 = 0.f;
        for (int r0 = 0; r0 < 320; r0 += 64) {
            __syncthreads();         // WAR on wt
            for (int e = tid; e < 4096; e += 256) {
                int h = e >> 6, rr = e & 63;
                int r = r0 + rr;
                wt[rr * 65 + h] = (r < NRBF_) ? Wd1[h * NRBF_ + r] : 0.f;
            }
            __syncthreads();         // RAW on wt
            if (live) {
                #pragma unroll
                for (int rr = 0; rr < 64; rr += 2) {
                    a0 = fmaf(wt[rr * 65 + lane],       rbf[sub * 320 + r0 + rr],     a0);
                    a1 = fmaf(wt[(rr + 1) * 65 + lane], rbf[sub * 320 + r0 + rr + 1], a1);
                }
            }
        }
        if (live) u[sub * 64 + lane] = sp_f(a0 + a1);
        __syncthreads();
        // stage Wd2^T into wt (reuse)
        for (int e = tid; e < 4096; e += 256) {
            int o = e >> 6, c = e & 63;
            wt[c * 65 + o] = Wd2[e];
        }
        __syncthreads();
        if (live) {
            float c0 = bd2[lane], c1 = 0.f;
            #pragma unroll
            for (int h1 = 0; h1 < 64; h1 += 2) {
                c0 = fmaf(wt[h1 * 65 + lane],       u[sub * 64 + h1],     c0);
                c1 = fmaf(wt[(h1 + 1) * 65 + lane], u[sub * 64 + h1 + 1], c1);
            }
            ws[T_OFF + s * 64 + lane] = sp_f(c0 + c1);
        }
    } else {
        // ---- transpose W2, W3 ----
        for (int e = tid; e < 4096; e += 256) {
            int o = e >> 6, c = e & 63;
            ws[W2T_OFF + c * 64 + o] = W2[e];
            ws[W3T_OFF + c * 64 + o] = W3[e];
        }
    }
}

// ---------------------------------------------------------------------------
// main: one block per (m, j).  agg[c] = sum_i v1[m,i,c] * lerp(T, d_ij)[c]
//       then v2 = sp(agg @ W2^T + b2); out = x + v2 @ W3^T + b3
// ---------------------------------------------------------------------------
__global__ __launch_bounds__(256)
void schnet_main(const float* __restrict__ x, const float* __restrict__ dist,
                 const float* __restrict__ b2, const float* __restrict__ b3,
                 const float* __restrict__ ws, float* __restrict__ out)
{
    __shared__ float sD[64];
    __shared__ float sRed[4 * 64];
    const int m   = blockIdx.x >> 6;
    const int j   = blockIdx.x & 63;
    const int tid = threadIdx.x;
    const int c   = tid & 63;        // channel this thread owns (lane)
    const int p   = tid >> 6;        // wave = i-quarter

    if (tid < 64) sD[tid] = dist[(m * ATOM_ + tid) * ATOM_ + j];
    __syncthreads();

    const float* Tb  = ws + T_OFF;
    const float* v1m = ws + V1_OFF + (m * 64 + p * 16) * 64;
    float acc = 0.f;
    #pragma unroll
    for (int ii = 0; ii < 16; ++ii) {
        float d  = sD[p * 16 + ii];                 // LDS broadcast
        float f  = d * INV_TSTEP;
        int   s  = min((int)f, TPTS - 2);
        float fr = f - (float)s;
        const float* Tr = Tb + s * 64;
        float t0 = Tr[c], t1 = Tr[64 + c];          // coalesced 256B rows
        float f2v = fmaf(fr, t1 - t0, t0);
        acc = fmaf(f2v, v1m[ii * 64 + c], acc);     // coalesced, L1/L2-hit
    }
    sRed[p * 64 + c] = acc;
    __syncthreads();
    if (tid < 64)
        sD[tid] = sRed[tid] + sRed[64 + tid] + sRed[128 + tid] + sRed[192 + tid];
    __syncthreads();

    // v2_pre = agg @ W2^T : thread (o=c, quarter=p) does 16 MACs, coalesced W2T
    {
        const float* W2t = ws + W2T_OFF;
        float s_ = 0.f;
        #pragma unroll
        for (int cc = 0; cc < 16; ++cc)
            s_ = fmaf(sD[16 * p + cc], W2t[(16 * p + cc) * 64 + c], s_);
        sRed[p * 64 + c] = s_;
    }
    __syncthreads();
    if (tid < 64)
        sD[tid] = sp_f(sRed[tid] + sRed[64 + tid] + sRed[128 + tid] + sRed[192 + tid] + b2[tid]);
    __syncthreads();
    {
        const float* W3t = ws + W3T_OFF;
        float s_ = 0.f;
        #pragma unroll
        for (int cc = 0; cc < 16; ++cc)
            s_ = fmaf(sD[16 * p + cc], W3t[(16 * p + cc) * 64 + c], s_);
        sRed[p * 64 + c] = s_;
    }
    __syncthreads();
    if (tid < 64) {
        float v_ = sRed[tid] + sRed[64 + tid] + sRed[128 + tid] + sRed[192 + tid] + b3[tid];
        out[(m * ATOM_ + j) * HID_ + tid] = v_ + x[(m * ATOM_ + j) * HID_ + tid];
    }
}

extern "C" void kernel_launch(void* const* d_in, const int* in_sizes, int n_in,
                              void* d_out, int out_size, void* d_ws, size_t ws_size,
                              hipStream_t stream) {
    const float* x   = (const float*)d_in[0];
    const float* dist= (const float*)d_in[1];
    const float* W1  = (const float*)d_in[2];
    const float* b1  = (const float*)d_in[3];
    const float* W2  = (const float*)d_in[4];
    const float* b2  = (const float*)d_in[5];
    const float* W3  = (const float*)d_in[6];
    const float* b3  = (const float*)d_in[7];
    const float* Wd1 = (const float*)d_in[8];
    const float* bd1 = (const float*)d_in[9];
    const float* Wd2 = (const float*)d_in[10];
    const float* bd2 = (const float*)d_in[11];
    float* out = (float*)d_out;
    float* ws  = (float*)d_ws;
    (void)in_sizes; (void)n_in; (void)out_size; (void)ws_size;
    // needs ~1.07 MB of d_ws (table + v1 + W2^T/W3^T)

    schnet_prep<<<dim3(MB_ + 501 + 1), dim3(256), 0, stream>>>(
        x, W1, b1, W2, W3, Wd1, bd1, Wd2, bd2, ws);
    schnet_main<<<dim3(MB_ * ATOM_), dim3(256), 0, stream>>>(
        x, dist, b2, b3, ws, out);
}

// Round 5
// 93.879 us; speedup vs baseline: 1.2915x; 1.2277x over previous
//
#include <hip/hip_runtime.h>
#include <math.h>

#define MB_    32
#define ATOM_  64
#define HID_   64
#define NRBF_  300
#define GAMMA_ 10.0f
#define RES_   0.1f

// filter table: f2(d) sampled at TPTS points, step TSTEP, domain [0, 10]
#define TPTS      2001
#define TSTEP     0.005f
#define INV_TSTEP 200.0f

// truncated RBF window: terms with |d - 0.1 r| > ~1.4 contribute < 5e-9
#define RWIN 28

// workspace layout (float offsets)
#define T_OFF   0
#define T_SZ    (TPTS * 64)          // 128064
#define V1_OFF  (T_OFF + T_SZ)       // 128064
#define V1_SZ   (MB_ * 64 * 64)      // 131072
#define W2T_OFF (V1_OFF + V1_SZ)     // 259136
#define W3T_OFF (W2T_OFF + 4096)     // 263232
// total 267328 floats = 1,069,312 bytes of d_ws

__device__ __forceinline__ float sp_f(float x) {
    return fmaxf(x, 0.f) + log1pf(__expf(-fabsf(x)));
}

// ---------------------------------------------------------------------------
// prep: blocks [0,32)   -> v1[m] = x[m] @ W1^T + b1   (4x4 register tile)
//       blocks [32,533) -> filter table rows, truncated-RBF, barrier-light
//       block  533      -> W2^T, W3^T for coalesced tail reads
// ---------------------------------------------------------------------------
__global__ __launch_bounds__(256)
void schnet_prep(const float* __restrict__ x,   const float* __restrict__ W1,
                 const float* __restrict__ b1,  const float* __restrict__ W2,
                 const float* __restrict__ W3,  const float* __restrict__ Wd1,
                 const float* __restrict__ bd1, const float* __restrict__ Wd2,
                 const float* __restrict__ bd2, float* __restrict__ ws)
{
    __shared__ float smem[8320];     // 33.3 KB, unioned between branches
    const int tid = threadIdx.x;
    const int b   = blockIdx.x;

    if (b < MB_) {
        // ---- v1 = x[m] @ W1^T + b1, 4x4 register tile per thread ----
        float* sx = smem;            // x[m]  [64][65] (pad -> <=2-way banks)
        float* sw = smem + 4160;     // W1    [64][65]
        const float* xm = x + b * 4096;
        for (int e = tid; e < 4096; e += 256) {
            int i = e >> 6, c = e & 63;
            sx[i * 65 + c] = xm[e];
            sw[i * 65 + c] = W1[e];
        }
        __syncthreads();
        const int tx = tid & 15;         // o-tile: o = 4*tx + bb
        const int ty = tid >> 4;         // i-tile: i = 4*ty + aa
        float acc[4][4];
        #pragma unroll
        for (int aa = 0; aa < 4; ++aa)
            #pragma unroll
            for (int bb = 0; bb < 4; ++bb)
                acc[aa][bb] = b1[4 * tx + bb];
        #pragma unroll 8
        for (int k = 0; k < 64; ++k) {
            float xa[4], wb[4];
            #pragma unroll
            for (int aa = 0; aa < 4; ++aa) xa[aa] = sx[(4 * ty + aa) * 65 + k];  // broadcast
            #pragma unroll
            for (int bb = 0; bb < 4; ++bb) wb[bb] = sw[(4 * tx + bb) * 65 + k];  // 2-way
            #pragma unroll
            for (int aa = 0; aa < 4; ++aa)
                #pragma unroll
                for (int bb = 0; bb < 4; ++bb)
                    acc[aa][bb] = fmaf(xa[aa], wb[bb], acc[aa][bb]);
        }
        #pragma unroll
        for (int aa = 0; aa < 4; ++aa) {
            float4 v = make_float4(acc[aa][0], acc[aa][1], acc[aa][2], acc[aa][3]);
            *(float4*)(ws + V1_OFF + (b * 64 + 4 * ty + aa) * 64 + 4 * tx) = v;
        }
    } else if (b < MB_ + 501) {
        // ---- table: one d-sample per wave, truncated RBF in registers ----
        float* su = smem;                // [4][64] per-wave u vectors
        const int sub = tid >> 6, c = tid & 63;
        const int s  = (b - MB_) * 4 + sub;
        const int se = min(s, TPTS - 1);         // dead waves compute, don't store
        const float d = se * TSTEP;

        int r0 = (int)ceilf((d - 1.35f) * 10.0f);
        r0 = max(r0, 0);                          // r0+RWIN-1 <= 114 < 300 always

        float a0 = bd1[c], a1 = 0.f;
        const float* wrow1 = Wd1 + c * NRBF_ + r0;
        #pragma unroll
        for (int k = 0; k < RWIN; k += 2) {
            float t0 = fmaf(-RES_, (float)(r0 + k),     d);
            float t1 = fmaf(-RES_, (float)(r0 + k + 1), d);
            float w0 = __expf(-GAMMA_ * t0 * t0);
            float w1 = __expf(-GAMMA_ * t1 * t1);
            a0 = fmaf(w0, wrow1[k],     a0);
            a1 = fmaf(w1, wrow1[k + 1], a1);
        }
        su[sub * 64 + c] = sp_f(a0 + a1);
        __syncthreads();

        // f2[o] = sp( sum_h Wd2[o][h] * u[h] + bd2[o] ), o = lane
        const float4* wrow2 = (const float4*)(Wd2 + c * 64);
        const float*  uu    = su + sub * 64;
        float s0 = bd2[c], s1 = 0.f, s2 = 0.f, s3 = 0.f;
        #pragma unroll
        for (int h4 = 0; h4 < 16; ++h4) {
            float4 wv = wrow2[h4];
            s0 = fmaf(wv.x, uu[4 * h4 + 0], s0);   // uu reads: all-lane broadcast
            s1 = fmaf(wv.y, uu[4 * h4 + 1], s1);
            s2 = fmaf(wv.z, uu[4 * h4 + 2], s2);
            s3 = fmaf(wv.w, uu[4 * h4 + 3], s3);
        }
        if (s < TPTS)
            ws[T_OFF + s * 64 + c] = sp_f((s0 + s1) + (s2 + s3));
    } else {
        // ---- transpose W2, W3 ----
        for (int e = tid; e < 4096; e += 256) {
            int o = e >> 6, c = e & 63;
            ws[W2T_OFF + c * 64 + o] = W2[e];
            ws[W3T_OFF + c * 64 + o] = W3[e];
        }
    }
}

// ---------------------------------------------------------------------------
// main: one block per (m, j).  agg[c] = sum_i v1[m,i,c] * lerp(T, d_ij)[c]
//       then v2 = sp(agg @ W2^T + b2); out = x + v2 @ W3^T + b3
// ---------------------------------------------------------------------------
__global__ __launch_bounds__(256)
void schnet_main(const float* __restrict__ x, const float* __restrict__ dist,
                 const float* __restrict__ b2, const float* __restrict__ b3,
                 const float* __restrict__ ws, float* __restrict__ out)
{
    __shared__ float sD[64];
    __shared__ float sRed[4 * 64];
    const int m   = blockIdx.x >> 6;
    const int j   = blockIdx.x & 63;
    const int tid = threadIdx.x;
    const int c   = tid & 63;        // channel this thread owns (lane)
    const int p   = tid >> 6;        // wave = i-quarter

    if (tid < 64) sD[tid] = dist[(m * ATOM_ + tid) * ATOM_ + j];
    __syncthreads();

    const float* Tb  = ws + T_OFF;
    const float* v1m = ws + V1_OFF + (m * 64 + p * 16) * 64;
    float acc = 0.f;
    #pragma unroll
    for (int ii = 0; ii < 16; ++ii) {
        float d  = sD[p * 16 + ii];                 // LDS broadcast
        float f  = d * INV_TSTEP;
        int   s  = min((int)f, TPTS - 2);
        float fr = f - (float)s;
        const float* Tr = Tb + s * 64;
        float t0 = Tr[c], t1 = Tr[64 + c];          // coalesced 256B rows
        float f2v = fmaf(fr, t1 - t0, t0);
        acc = fmaf(f2v, v1m[ii * 64 + c], acc);     // coalesced, L1/L2-hit
    }
    sRed[p * 64 + c] = acc;
    __syncthreads();
    if (tid < 64)
        sD[tid] = sRed[tid] + sRed[64 + tid] + sRed[128 + tid] + sRed[192 + tid];
    __syncthreads();

    // v2_pre = agg @ W2^T : thread (o=c, quarter=p) does 16 MACs, coalesced W2T
    {
        const float* W2t = ws + W2T_OFF;
        float s_ = 0.f;
        #pragma unroll
        for (int cc = 0; cc < 16; ++cc)
            s_ = fmaf(sD[16 * p + cc], W2t[(16 * p + cc) * 64 + c], s_);
        sRed[p * 64 + c] = s_;
    }
    __syncthreads();
    if (tid < 64)
        sD[tid] = sp_f(sRed[tid] + sRed[64 + tid] + sRed[128 + tid] + sRed[192 + tid] + b2[tid]);
    __syncthreads();
    {
        const float* W3t = ws + W3T_OFF;
        float s_ = 0.f;
        #pragma unroll
        for (int cc = 0; cc < 16; ++cc)
            s_ = fmaf(sD[16 * p + cc], W3t[(16 * p + cc) * 64 + c], s_);
        sRed[p * 64 + c] = s_;
    }
    __syncthreads();
    if (tid < 64) {
        float v_ = sRed[tid] + sRed[64 + tid] + sRed[128 + tid] + sRed[192 + tid] + b3[tid];
        out[(m * ATOM_ + j) * HID_ + tid] = v_ + x[(m * ATOM_ + j) * HID_ + tid];
    }
}

extern "C" void kernel_launch(void* const* d_in, const int* in_sizes, int n_in,
                              void* d_out, int out_size, void* d_ws, size_t ws_size,
                              hipStream_t stream) {
    const float* x   = (const float*)d_in[0];
    const float* dist= (const float*)d_in[1];
    const float* W1  = (const float*)d_in[2];
    const float* b1  = (const float*)d_in[3];
    const float* W2  = (const float*)d_in[4];
    const float* b2  = (const float*)d_in[5];
    const float* W3  = (const float*)d_in[6];
    const float* b3  = (const float*)d_in[7];
    const float* Wd1 = (const float*)d_in[8];
    const float* bd1 = (const float*)d_in[9];
    const float* Wd2 = (const float*)d_in[10];
    const float* bd2 = (const float*)d_in[11];
    float* out = (float*)d_out;
    float* ws  = (float*)d_ws;
    (void)in_sizes; (void)n_in; (void)out_size; (void)ws_size;
    // needs ~1.07 MB of d_ws (table + v1 + W2^T/W3^T)

    schnet_prep<<<dim3(MB_ + 501 + 1), dim3(256), 0, stream>>>(
        x, W1, b1, W2, W3, Wd1, bd1, Wd2, bd2, ws);
    schnet_main<<<dim3(MB_ * ATOM_), dim3(256), 0, stream>>>(
        x, dist, b2, b3, ws, out);
}